// Round 16
// baseline (233.106 us; speedup 1.0000x reference)
//
#include <hip/hip_runtime.h>

#define N_NODES 50000
#define N_EDGES 800000
#define N_LABEL 200000
#define ROW_BLOCKS 782   // ceil(50000/64)

typedef __attribute__((ext_vector_type(4))) float f32x4;
typedef _Float16 f16;
typedef __attribute__((ext_vector_type(8))) _Float16 f16x8;

// Sliced feature layout (R14): A/B = [4][N_NODES][32] f16, 64B line-packed per slice.

// ---------------- pre: zero cnt/cnt2 | W transpose/split | pack edges to ushort ----------
// blocks [0,98): zero; [98,162): wprep; [162,3287): pack
__global__ __launch_bounds__(256)
void k_pre(int4* __restrict__ p,
           const float* __restrict__ W1, const float* __restrict__ W2,
           const float* __restrict__ W3,
           f16* WT1h, f16* WT1l, f16* WT2h, f16* WT2l, f16* WT3h, f16* WT3l,
           const int* __restrict__ esrc, const int* __restrict__ edst,
           unsigned short* __restrict__ src16, unsigned short* __restrict__ dst16) {
    int b = blockIdx.x, tid = threadIdx.x;
    if (b < 98) {
        int i = b * 256 + tid;
        if (i < 25024) p[i] = int4{0, 0, 0, 0};
    } else if (b < 162) {
        int t = (b - 98) * 256 + tid;          // < 16384
        int c = t >> 7, k = t & 127;
        float w = W1[k * 128 + c];
        f16 h = (f16)w;
        WT1h[c * 128 + k] = h; WT1l[c * 128 + k] = (f16)(w - (float)h);
        w = W2[k * 128 + c];
        h = (f16)w;
        WT2h[c * 128 + k] = h; WT2l[c * 128 + k] = (f16)(w - (float)h);
        if (c < 64) {
            w = W3[k * 64 + c];
            h = (f16)w;
            WT3h[c * 128 + k] = h; WT3l[c * 128 + k] = (f16)(w - (float)h);
        }
    } else {
        int i = (b - 162) * 256 + tid;         // < 800,000 exactly
        src16[i] = (unsigned short)esrc[i];
        dst16[i] = (unsigned short)edst[i];
    }
}

// ---------------- XCD-partitioned deg count (ushort reads) ----------------
__global__ __launch_bounds__(256)
void k_deg(const unsigned short* __restrict__ dst16, int* cnt) {
    int vb = blockIdx.x;
    int g = vb & 7;
    int i = (vb >> 3) * 256 + threadIdx.x;     // < 800,000 exactly
    int d = dst16[i];
    if ((unsigned)(d - g * 6250) < 6250u) atomicAdd(&cnt[d], 1);
}

// ---------------- merged scan: dinv + off in one kernel ----------------
// block b: add0 = sum(cnt[0 .. b*256)) via strided per-thread sums (L2-hot),
// then local inclusive scan of its 256 cnt values.
__global__ __launch_bounds__(256)
void k_offs(const int* __restrict__ cnt, float* __restrict__ dinv,
            int* __restrict__ off, int N) {
    __shared__ int wsum[4];
    __shared__ int add0_s;
    int b = blockIdx.x, t = threadIdx.x;
    // phase A: prefix over earlier blocks
    int s = 0;
    for (int k = t; k < b * 256; k += 256) s += cnt[k];
#pragma unroll
    for (int d = 1; d < 64; d <<= 1) s += __shfl_xor(s, d, 64);
    if ((t & 63) == 0) wsum[t >> 6] = s;
    __syncthreads();
    if (t == 0) add0_s = wsum[0] + wsum[1] + wsum[2] + wsum[3];
    __syncthreads();
    int add = add0_s;
    __syncthreads();   // protect wsum reuse
    // phase B: local scan + dinv
    int i = b * 256 + t;
    int v = (i < N) ? cnt[i] : 0;
    if (i < N) dinv[i] = rsqrtf((float)v + 1.0f);
    int lane = t & 63, w = t >> 6;
    int sv = v;
#pragma unroll
    for (int d = 1; d < 64; d <<= 1) {
        int u = __shfl_up(sv, d, 64);
        if (lane >= d) sv += u;
    }
    if (lane == 63) wsum[w] = sv;
    __syncthreads();
    for (int ww = 0; ww < w; ++ww) add += wsum[ww];
    if (i < N) off[i + 1] = add + sv;
    if (i == 0) off[0] = 0;
}

// ---------------- XCD-partitioned bucket fill (ushort) ----------------
__global__ __launch_bounds__(256)
void k_bucket(const unsigned short* __restrict__ src16,
              const unsigned short* __restrict__ dst16,
              const int* __restrict__ off, int* cnt2, unsigned short* __restrict__ csr) {
    int vb = blockIdx.x;
    int g = vb & 7;
    int i = (vb >> 3) * 256 + threadIdx.x;     // < 800,000 exactly
    int d = dst16[i];
    if ((unsigned)(d - g * 6250) < 6250u) {
        int slot = off[d] + atomicAdd(&cnt2[d], 1);
        csr[slot] = src16[i];
    }
}

// ---------------- GEMM layer 1: fp32 x, in-register fp16 split, W in LDS, sliced out ----
__global__ __launch_bounds__(256)
void k_gemm1(const float* __restrict__ x,
             const f16* __restrict__ WTh, const f16* __restrict__ WTl,
             const float* __restrict__ dinv, f16* __restrict__ As, int N) {
    constexpr int NCB = 4;
    __shared__ f16 Hs[64 * 136];
    __shared__ f16 Ls[64 * 136];
    int b = blockIdx.x;
    int c0 = (b & 1) * 64;
    int t = threadIdx.x;

#pragma unroll
    for (int i = 0; i < 4; ++i) {
        int ch = t + i * 256;
        int col = ch >> 4;
        int kc = (ch & 15) * 8;
        *(f16x8*)&Hs[col * 136 + kc] = *(const f16x8*)&WTh[(long)(c0 + col) * 128 + kc];
        *(f16x8*)&Ls[col * 136 + kc] = *(const f16x8*)&WTl[(long)(c0 + col) * 128 + kc];
    }

    int wv = t >> 6, l = t & 63;
    int r0w = (b >> 1) * 64 + wv * 16;
    int arow = r0w + (l & 15);
    if (arow >= N) arow = N - 1;
    int kb = (l >> 4) * 8;

    f16x8 ah[4], al[4];
#pragma unroll
    for (int ks = 0; ks < 4; ++ks) {
        const float* xp = &x[(long)arow * 128 + ks * 32 + kb];
        float4 a0 = *(const float4*)xp;
        float4 a1 = *(const float4*)(xp + 4);
        float fv[8] = {a0.x, a0.y, a0.z, a0.w, a1.x, a1.y, a1.z, a1.w};
#pragma unroll
        for (int j = 0; j < 8; ++j) {
            f16 h = (f16)fv[j];
            ah[ks][j] = h;
            al[ks][j] = (f16)(fv[j] - (float)h);
        }
    }
    __syncthreads();

    f32x4 acc[NCB];
#pragma unroll
    for (int cb = 0; cb < NCB; ++cb) acc[cb] = f32x4{0.f, 0.f, 0.f, 0.f};
#pragma unroll
    for (int ks = 0; ks < 4; ++ks) {
#pragma unroll
        for (int cb = 0; cb < NCB; ++cb) {
            int wi = (cb * 16 + (l & 15)) * 136 + ks * 32 + kb;
            f16x8 bh = *(const f16x8*)&Hs[wi];
            f16x8 bl = *(const f16x8*)&Ls[wi];
            acc[cb] = __builtin_amdgcn_mfma_f32_16x16x32_f16(ah[ks], bh, acc[cb], 0, 0, 0);
            acc[cb] = __builtin_amdgcn_mfma_f32_16x16x32_f16(ah[ks], bl, acc[cb], 0, 0, 0);
            acc[cb] = __builtin_amdgcn_mfma_f32_16x16x32_f16(al[ks], bh, acc[cb], 0, 0, 0);
        }
    }
    // C/D layout: col = l&15, row = (l>>4)*4 + i   [verified m89]
    int rbase = r0w + (l >> 4) * 4;
    float dv[4];
#pragma unroll
    for (int i = 0; i < 4; ++i) dv[i] = (rbase + i < N) ? dinv[rbase + i] : 0.f;
#pragma unroll
    for (int cb = 0; cb < NCB; ++cb) {
        int fc = c0 + cb * 16 + (l & 15);
        long sb = (long)(fc >> 5) * N_NODES * 32 + (fc & 31);
#pragma unroll
        for (int i = 0; i < 4; ++i) {
            int r = rbase + i;
            if (r < N) As[sb + (long)r * 32] = (f16)(acc[cb][i] * dv[i]);
        }
    }
}

// ---------------- GEMM layers 2/3: sliced in, 2 MFMAs, W in LDS, sliced out --------
template<int M>
__global__ __launch_bounds__(256)
void k_gemm23(const f16* __restrict__ Bs,
              const f16* __restrict__ WTh, const f16* __restrict__ WTl,
              const float* __restrict__ dinv, f16* __restrict__ As, int N) {
    constexpr int NCB = M / 32;
    constexpr int HC = M / 2;
    __shared__ f16 Hs[HC * 136];
    __shared__ f16 Ls[HC * 136];
    int b = blockIdx.x;
    int c0 = (b & 1) * HC;
    int t = threadIdx.x;

#pragma unroll
    for (int i = 0; i < HC / 16; ++i) {
        int ch = t + i * 256;
        int col = ch >> 4;
        int kc = (ch & 15) * 8;
        *(f16x8*)&Hs[col * 136 + kc] = *(const f16x8*)&WTh[(long)(c0 + col) * 128 + kc];
        *(f16x8*)&Ls[col * 136 + kc] = *(const f16x8*)&WTl[(long)(c0 + col) * 128 + kc];
    }

    int wv = t >> 6, l = t & 63;
    int r0w = (b >> 1) * 64 + wv * 16;
    int arow = r0w + (l & 15);
    if (arow >= N) arow = N - 1;
    int kb = (l >> 4) * 8;

    f16x8 a[4];
#pragma unroll
    for (int ks = 0; ks < 4; ++ks)
        a[ks] = *(const f16x8*)&Bs[((long)ks * N_NODES + arow) * 32 + kb];
    __syncthreads();

    f32x4 acc[NCB];
#pragma unroll
    for (int cb = 0; cb < NCB; ++cb) acc[cb] = f32x4{0.f, 0.f, 0.f, 0.f};
#pragma unroll
    for (int ks = 0; ks < 4; ++ks) {
#pragma unroll
        for (int cb = 0; cb < NCB; ++cb) {
            int wi = (cb * 16 + (l & 15)) * 136 + ks * 32 + kb;
            f16x8 bh = *(const f16x8*)&Hs[wi];
            f16x8 bl = *(const f16x8*)&Ls[wi];
            acc[cb] = __builtin_amdgcn_mfma_f32_16x16x32_f16(a[ks], bh, acc[cb], 0, 0, 0);
            acc[cb] = __builtin_amdgcn_mfma_f32_16x16x32_f16(a[ks], bl, acc[cb], 0, 0, 0);
        }
    }
    int rbase = r0w + (l >> 4) * 4;
    float dv[4];
#pragma unroll
    for (int i = 0; i < 4; ++i) dv[i] = (rbase + i < N) ? dinv[rbase + i] : 0.f;
#pragma unroll
    for (int cb = 0; cb < NCB; ++cb) {
        int fc = c0 + cb * 16 + (l & 15);
        long sb = (long)(fc >> 5) * N_NODES * 32 + (fc & 31);
#pragma unroll
        for (int i = 0; i < 4; ++i) {
            int r = rbase + i;
            if (r < N) As[sb + (long)r * 32] = (f16)(acc[cb][i] * dv[i]);
        }
    }
}

// ---------------- sliced XCD-partitioned gather (M=128): A_s -> B_s ----------------
__global__ __launch_bounds__(256)
void k_gather128(const f16* __restrict__ As, const int* __restrict__ off,
                 const unsigned short* __restrict__ csr, const float* __restrict__ dinv,
                 const float* __restrict__ bias, f16* __restrict__ Bs) {
    int vb = blockIdx.x;
    int g = vb & 7, blk = vb >> 3;
    int t = threadIdx.x;
    int nl = blk * 64 + (t >> 2);
    if (nl >= 25000) return;
    int node = (g & 1) * 25000 + nl;
    int cs = g >> 1;
    int qq = (t & 3) * 8;
    const f16* Aq = As + (long)cs * N_NODES * 32 + qq;

    float acc[8];
    {
        f16x8 v = *(const f16x8*)&Aq[(long)node * 32];
#pragma unroll
        for (int c = 0; c < 8; ++c) acc[c] = (float)v[c];
    }
    int j = off[node], j1 = off[node + 1];
    for (; j + 8 <= j1; j += 8) {
        int s0 = csr[j + 0], s1 = csr[j + 1], s2 = csr[j + 2], s3 = csr[j + 3];
        int s4 = csr[j + 4], s5 = csr[j + 5], s6 = csr[j + 6], s7 = csr[j + 7];
        f16x8 v0 = *(const f16x8*)&Aq[(long)s0 * 32];
        f16x8 v1 = *(const f16x8*)&Aq[(long)s1 * 32];
        f16x8 v2 = *(const f16x8*)&Aq[(long)s2 * 32];
        f16x8 v3 = *(const f16x8*)&Aq[(long)s3 * 32];
        f16x8 v4 = *(const f16x8*)&Aq[(long)s4 * 32];
        f16x8 v5 = *(const f16x8*)&Aq[(long)s5 * 32];
        f16x8 v6 = *(const f16x8*)&Aq[(long)s6 * 32];
        f16x8 v7 = *(const f16x8*)&Aq[(long)s7 * 32];
#pragma unroll
        for (int c = 0; c < 8; ++c)
            acc[c] += ((float)v0[c] + (float)v1[c] + (float)v2[c] + (float)v3[c])
                    + ((float)v4[c] + (float)v5[c] + (float)v6[c] + (float)v7[c]);
    }
    for (; j + 2 <= j1; j += 2) {
        int s0 = csr[j + 0], s1 = csr[j + 1];
        f16x8 v0 = *(const f16x8*)&Aq[(long)s0 * 32];
        f16x8 v1 = *(const f16x8*)&Aq[(long)s1 * 32];
#pragma unroll
        for (int c = 0; c < 8; ++c) acc[c] += (float)v0[c] + (float)v1[c];
    }
    if (j < j1) {
        int s = csr[j];
        f16x8 v = *(const f16x8*)&Aq[(long)s * 32];
#pragma unroll
        for (int c = 0; c < 8; ++c) acc[c] += (float)v[c];
    }
    float sc = dinv[node];
    int q = cs * 32 + qq;
    float4 bb0 = *(const float4*)&bias[q];
    float4 bb1 = *(const float4*)&bias[q + 4];
    float bv[8] = {bb0.x, bb0.y, bb0.z, bb0.w, bb1.x, bb1.y, bb1.z, bb1.w};
    f16x8 o;
#pragma unroll
    for (int c = 0; c < 8; ++c) o[c] = (f16)fmaxf(acc[c] * sc + bv[c], 0.f);
    *(f16x8*)&Bs[((long)cs * N_NODES + node) * 32 + qq] = o;
}

// ---------------- sliced gather (M=64): A3_s (2 slices) -> z [node][64] fp32 ----------
__global__ __launch_bounds__(256)
void k_gather64(const f16* __restrict__ As, const int* __restrict__ off,
                const unsigned short* __restrict__ csr, const float* __restrict__ dinv,
                const float* __restrict__ bias, float* __restrict__ z) {
    int vb = blockIdx.x;
    int g = vb & 7, blk = vb >> 3;
    int t = threadIdx.x;
    int nl = blk * 64 + (t >> 2);
    if (nl >= 12500) return;
    int node = (g >> 1) * 12500 + nl;
    int cs = g & 1;
    int qq = (t & 3) * 8;
    const f16* Aq = As + (long)cs * N_NODES * 32 + qq;

    float acc[8];
    {
        f16x8 v = *(const f16x8*)&Aq[(long)node * 32];
#pragma unroll
        for (int c = 0; c < 8; ++c) acc[c] = (float)v[c];
    }
    int j = off[node], j1 = off[node + 1];
    for (; j + 8 <= j1; j += 8) {
        int s0 = csr[j + 0], s1 = csr[j + 1], s2 = csr[j + 2], s3 = csr[j + 3];
        int s4 = csr[j + 4], s5 = csr[j + 5], s6 = csr[j + 6], s7 = csr[j + 7];
        f16x8 v0 = *(const f16x8*)&Aq[(long)s0 * 32];
        f16x8 v1 = *(const f16x8*)&Aq[(long)s1 * 32];
        f16x8 v2 = *(const f16x8*)&Aq[(long)s2 * 32];
        f16x8 v3 = *(const f16x8*)&Aq[(long)s3 * 32];
        f16x8 v4 = *(const f16x8*)&Aq[(long)s4 * 32];
        f16x8 v5 = *(const f16x8*)&Aq[(long)s5 * 32];
        f16x8 v6 = *(const f16x8*)&Aq[(long)s6 * 32];
        f16x8 v7 = *(const f16x8*)&Aq[(long)s7 * 32];
#pragma unroll
        for (int c = 0; c < 8; ++c)
            acc[c] += ((float)v0[c] + (float)v1[c] + (float)v2[c] + (float)v3[c])
                    + ((float)v4[c] + (float)v5[c] + (float)v6[c] + (float)v7[c]);
    }
    for (; j + 2 <= j1; j += 2) {
        int s0 = csr[j + 0], s1 = csr[j + 1];
        f16x8 v0 = *(const f16x8*)&Aq[(long)s0 * 32];
        f16x8 v1 = *(const f16x8*)&Aq[(long)s1 * 32];
#pragma unroll
        for (int c = 0; c < 8; ++c) acc[c] += (float)v0[c] + (float)v1[c];
    }
    if (j < j1) {
        int s = csr[j];
        f16x8 v = *(const f16x8*)&Aq[(long)s * 32];
#pragma unroll
        for (int c = 0; c < 8; ++c) acc[c] += (float)v[c];
    }
    float sc = dinv[node];
    int q = cs * 32 + qq;
    float4 bb0 = *(const float4*)&bias[q];
    float4 bb1 = *(const float4*)&bias[q + 4];
    float4 o0, o1;
    o0.x = acc[0] * sc + bb0.x; o0.y = acc[1] * sc + bb0.y;
    o0.z = acc[2] * sc + bb0.z; o0.w = acc[3] * sc + bb0.w;
    o1.x = acc[4] * sc + bb1.x; o1.y = acc[5] * sc + bb1.y;
    o1.z = acc[6] * sc + bb1.z; o1.w = acc[7] * sc + bb1.w;
    *(float4*)&z[(long)node * 64 + q] = o0;
    *(float4*)&z[(long)node * 64 + q + 4] = o1;
}

// ---------------- decode: out[i] = dot64(z[a], z[b]) ----------------
__global__ void k_decode(const float* __restrict__ z, const int* __restrict__ eli,
                         float* __restrict__ out, int L) {
    int t = blockIdx.x * blockDim.x + threadIdx.x;
    int e = t >> 4;
    int lane = t & 15;
    if (e >= L) return;
    int a = eli[e], b = eli[L + e];
    float4 va = *(const float4*)&z[(long)a * 64 + lane * 4];
    float4 vb = *(const float4*)&z[(long)b * 64 + lane * 4];
    float s = va.x * vb.x + va.y * vb.y + va.z * vb.z + va.w * vb.w;
    s += __shfl_xor(s, 1, 16);
    s += __shfl_xor(s, 2, 16);
    s += __shfl_xor(s, 4, 16);
    s += __shfl_xor(s, 8, 16);
    if (lane == 0) out[e] = s;
}

extern "C" void kernel_launch(void* const* d_in, const int* in_sizes, int n_in,
                              void* d_out, int out_size, void* d_ws, size_t ws_size,
                              hipStream_t stream) {
    const float* x   = (const float*)d_in[0];
    const float* W1  = (const float*)d_in[1];
    const float* b1  = (const float*)d_in[2];
    const float* W2  = (const float*)d_in[3];
    const float* b2  = (const float*)d_in[4];
    const float* W3  = (const float*)d_in[5];
    const float* b3  = (const float*)d_in[6];
    const int*   ei  = (const int*)d_in[7];
    const int*   eli = (const int*)d_in[8];
    float* out = (float*)d_out;

    char* ws = (char*)d_ws;
    float* dinv = (float*)ws;                  ws += 50048 * 4;
    f16*   A    = (f16*)ws;                    ws += (long)N_NODES * 128 * 2;   // sliced
    f16*   B    = (f16*)ws;                    ws += (long)N_NODES * 128 * 2;   // sliced
    float* z    = (float*)ws;                  ws += (long)N_NODES * 64 * 4;
    int*   cnt  = (int*)ws;                    ws += 50048 * 4;
    int*   cnt2 = (int*)ws;                    ws += 50048 * 4;   // contiguous with cnt
    int*   off  = (int*)ws;                    ws += 50048 * 4;
    unsigned short* csr   = (unsigned short*)ws; ws += (long)N_EDGES * 2;
    unsigned short* src16 = (unsigned short*)ws; ws += (long)N_EDGES * 2;
    unsigned short* dst16 = (unsigned short*)ws; ws += (long)N_EDGES * 2;
    f16*   WT1h = (f16*)ws;                    ws += 16384 * 2;
    f16*   WT1l = (f16*)ws;                    ws += 16384 * 2;
    f16*   WT2h = (f16*)ws;                    ws += 16384 * 2;
    f16*   WT2l = (f16*)ws;                    ws += 16384 * 2;
    f16*   WT3h = (f16*)ws;                    ws += 8192 * 2;
    f16*   WT3l = (f16*)ws;                    ws += 8192 * 2;

    const int* esrc = ei;
    const int* edst = ei + N_EDGES;

    const int NB = (N_NODES + 255) / 256;  // 196

    // pre (zero | wprep | pack) -> deg -> offs (dinv+scan) -> bucket
    k_pre   <<<3287, 256, 0, stream>>>((int4*)cnt, W1, W2, W3,
                                       WT1h, WT1l, WT2h, WT2l, WT3h, WT3l,
                                       esrc, edst, src16, dst16);
    k_deg   <<<25000, 256, 0, stream>>>(dst16, cnt);
    k_offs  <<<NB, 256, 0, stream>>>(cnt, dinv, off, N_NODES);
    k_bucket<<<25000, 256, 0, stream>>>(src16, dst16, off, cnt2, csr);

    // layer 1
    k_gemm1<<<ROW_BLOCKS * 2, 256, 0, stream>>>(x, WT1h, WT1l, dinv, A, N_NODES);
    k_gather128<<<391 * 8, 256, 0, stream>>>(A, off, csr, dinv, b1, B);
    // layer 2
    k_gemm23<128><<<ROW_BLOCKS * 2, 256, 0, stream>>>(B, WT2h, WT2l, dinv, A, N_NODES);
    k_gather128<<<391 * 8, 256, 0, stream>>>(A, off, csr, dinv, b2, B);
    // layer 3 (M=64, 2 slices, no relu, fp32 z out)
    k_gemm23<64><<<ROW_BLOCKS * 2, 256, 0, stream>>>(B, WT3h, WT3l, dinv, A, N_NODES);
    k_gather64<<<196 * 8, 256, 0, stream>>>(A, off, csr, dinv, b3, z);

    // decode
    k_decode<<<(N_LABEL * 16 + 255) / 256, 256, 0, stream>>>(z, eli, out, N_LABEL);
}

// Round 17
// 204.938 us; speedup vs baseline: 1.1374x; 1.1374x over previous
//
#include <hip/hip_runtime.h>

#define N_NODES 50000
#define N_EDGES 800000
#define N_LABEL 200000
#define ROW_BLOCKS 782   // ceil(50000/64)

typedef __attribute__((ext_vector_type(4))) float f32x4;
typedef _Float16 f16;
typedef __attribute__((ext_vector_type(8))) _Float16 f16x8;

// Sliced feature layout (R14): A/B = [4][N_NODES][32] f16, 64B line-packed per slice.
// z = [node][64] f16 (128B/row) — decode is fetch-bound; fp16 halves its traffic.

// ---------------- zero cnt+cnt2 ----------------
__global__ __launch_bounds__(256)
void k_zero(int4* __restrict__ p, int n4) {
    int i = blockIdx.x * 256 + threadIdx.x;
    if (i < n4) p[i] = int4{0, 0, 0, 0};
}

// ---------------- prep: W transpose/split fp16 hi+lo | XCD-partitioned deg_count ----------
__global__ __launch_bounds__(256)
void k_prep(const float* __restrict__ W1, const float* __restrict__ W2,
            const float* __restrict__ W3,
            f16* WT1h, f16* WT1l, f16* WT2h, f16* WT2l, f16* WT3h, f16* WT3l,
            const int* __restrict__ dst, int* cnt) {
    int b = blockIdx.x, tid = threadIdx.x;
    if (b < 64) {
        int t = b * 256 + tid;                 // < 16384
        int c = t >> 7, k = t & 127;
        float w = W1[k * 128 + c];
        f16 h = (f16)w;
        WT1h[c * 128 + k] = h; WT1l[c * 128 + k] = (f16)(w - (float)h);
        w = W2[k * 128 + c];
        h = (f16)w;
        WT2h[c * 128 + k] = h; WT2l[c * 128 + k] = (f16)(w - (float)h);
        if (c < 64) {
            w = W3[k * 64 + c];
            h = (f16)w;
            WT3h[c * 128 + k] = h; WT3l[c * 128 + k] = (f16)(w - (float)h);
        }
    } else {
        int vb = b - 64;                       // [0, 25000)
        int g = vb & 7;
        int i = (vb >> 3) * 256 + tid;         // < 800,000 exactly
        int d = dst[i];
        if ((unsigned)(d - g * 6250) < 6250u) atomicAdd(&cnt[d], 1);
    }
}

// ---------------- scan chain ----------------
__global__ __launch_bounds__(256)
void k_partial(const int* __restrict__ cnt, float* __restrict__ dinv,
               int* __restrict__ bsum, int N) {
    __shared__ int wsum[4];
    int b = blockIdx.x, t = threadIdx.x;
    int i = b * 256 + t;
    int v = (i < N) ? cnt[i] : 0;
    if (i < N) dinv[i] = rsqrtf((float)v + 1.0f);
    int s = v;
#pragma unroll
    for (int d = 1; d < 64; d <<= 1) s += __shfl_xor(s, d, 64);
    if ((t & 63) == 0) wsum[t >> 6] = s;
    __syncthreads();
    if (t == 0) bsum[b] = wsum[0] + wsum[1] + wsum[2] + wsum[3];
}

__global__ __launch_bounds__(256)
void k_offsets(const int* __restrict__ cnt, const int* __restrict__ bsum,
               int* __restrict__ off, int N, int NB) {
    __shared__ int wsum[4];
    __shared__ int add0_s;
    int b = blockIdx.x, t = threadIdx.x;
    int v0 = (t < b && t < NB) ? bsum[t] : 0;
    int s0 = v0;
#pragma unroll
    for (int d = 1; d < 64; d <<= 1) s0 += __shfl_xor(s0, d, 64);
    if ((t & 63) == 0) wsum[t >> 6] = s0;
    __syncthreads();
    if (t == 0) add0_s = wsum[0] + wsum[1] + wsum[2] + wsum[3];
    __syncthreads();
    int add = add0_s;
    __syncthreads();
    int i = b * 256 + t;
    int v = (i < N) ? cnt[i] : 0;
    int lane = t & 63, w = t >> 6;
    int sv = v;
#pragma unroll
    for (int d = 1; d < 64; d <<= 1) {
        int u = __shfl_up(sv, d, 64);
        if (lane >= d) sv += u;
    }
    if (lane == 63) wsum[w] = sv;
    __syncthreads();
    for (int ww = 0; ww < w; ++ww) add += wsum[ww];
    if (i < N) off[i + 1] = add + sv;
    if (i == 0) off[0] = 0;
}

// ---------------- XCD-partitioned bucket fill ----------------
__global__ __launch_bounds__(256)
void k_bucket(const int* __restrict__ srcv, const int* __restrict__ dstv,
              const int* __restrict__ off, int* cnt2, unsigned short* __restrict__ csr) {
    int vb = blockIdx.x;
    int g = vb & 7;
    int i = (vb >> 3) * 256 + threadIdx.x;   // < 800,000 exactly
    int d = dstv[i];
    if ((unsigned)(d - g * 6250) < 6250u) {
        int slot = off[d] + atomicAdd(&cnt2[d], 1);
        csr[slot] = (unsigned short)srcv[i];
    }
}

// ---------------- GEMM layer 1: fp32 x, in-register fp16 split, W in LDS, sliced out ----
__global__ __launch_bounds__(256)
void k_gemm1(const float* __restrict__ x,
             const f16* __restrict__ WTh, const f16* __restrict__ WTl,
             const float* __restrict__ dinv, f16* __restrict__ As, int N) {
    constexpr int NCB = 4;
    __shared__ f16 Hs[64 * 136];
    __shared__ f16 Ls[64 * 136];
    int b = blockIdx.x;
    int c0 = (b & 1) * 64;
    int t = threadIdx.x;

#pragma unroll
    for (int i = 0; i < 4; ++i) {
        int ch = t + i * 256;
        int col = ch >> 4;
        int kc = (ch & 15) * 8;
        *(f16x8*)&Hs[col * 136 + kc] = *(const f16x8*)&WTh[(long)(c0 + col) * 128 + kc];
        *(f16x8*)&Ls[col * 136 + kc] = *(const f16x8*)&WTl[(long)(c0 + col) * 128 + kc];
    }

    int wv = t >> 6, l = t & 63;
    int r0w = (b >> 1) * 64 + wv * 16;
    int arow = r0w + (l & 15);
    if (arow >= N) arow = N - 1;
    int kb = (l >> 4) * 8;

    f16x8 ah[4], al[4];
#pragma unroll
    for (int ks = 0; ks < 4; ++ks) {
        const float* xp = &x[(long)arow * 128 + ks * 32 + kb];
        float4 a0 = *(const float4*)xp;
        float4 a1 = *(const float4*)(xp + 4);
        float fv[8] = {a0.x, a0.y, a0.z, a0.w, a1.x, a1.y, a1.z, a1.w};
#pragma unroll
        for (int j = 0; j < 8; ++j) {
            f16 h = (f16)fv[j];
            ah[ks][j] = h;
            al[ks][j] = (f16)(fv[j] - (float)h);
        }
    }
    __syncthreads();

    f32x4 acc[NCB];
#pragma unroll
    for (int cb = 0; cb < NCB; ++cb) acc[cb] = f32x4{0.f, 0.f, 0.f, 0.f};
#pragma unroll
    for (int ks = 0; ks < 4; ++ks) {
#pragma unroll
        for (int cb = 0; cb < NCB; ++cb) {
            int wi = (cb * 16 + (l & 15)) * 136 + ks * 32 + kb;
            f16x8 bh = *(const f16x8*)&Hs[wi];
            f16x8 bl = *(const f16x8*)&Ls[wi];
            acc[cb] = __builtin_amdgcn_mfma_f32_16x16x32_f16(ah[ks], bh, acc[cb], 0, 0, 0);
            acc[cb] = __builtin_amdgcn_mfma_f32_16x16x32_f16(ah[ks], bl, acc[cb], 0, 0, 0);
            acc[cb] = __builtin_amdgcn_mfma_f32_16x16x32_f16(al[ks], bh, acc[cb], 0, 0, 0);
        }
    }
    // C/D layout: col = l&15, row = (l>>4)*4 + i   [verified m89]
    int rbase = r0w + (l >> 4) * 4;
    float dv[4];
#pragma unroll
    for (int i = 0; i < 4; ++i) dv[i] = (rbase + i < N) ? dinv[rbase + i] : 0.f;
#pragma unroll
    for (int cb = 0; cb < NCB; ++cb) {
        int fc = c0 + cb * 16 + (l & 15);
        long sb = (long)(fc >> 5) * N_NODES * 32 + (fc & 31);
#pragma unroll
        for (int i = 0; i < 4; ++i) {
            int r = rbase + i;
            if (r < N) As[sb + (long)r * 32] = (f16)(acc[cb][i] * dv[i]);
        }
    }
}

// ---------------- GEMM layers 2/3: sliced in, 2 MFMAs, W in LDS, sliced out --------
template<int M>
__global__ __launch_bounds__(256)
void k_gemm23(const f16* __restrict__ Bs,
              const f16* __restrict__ WTh, const f16* __restrict__ WTl,
              const float* __restrict__ dinv, f16* __restrict__ As, int N) {
    constexpr int NCB = M / 32;
    constexpr int HC = M / 2;
    __shared__ f16 Hs[HC * 136];
    __shared__ f16 Ls[HC * 136];
    int b = blockIdx.x;
    int c0 = (b & 1) * HC;
    int t = threadIdx.x;

#pragma unroll
    for (int i = 0; i < HC / 16; ++i) {
        int ch = t + i * 256;
        int col = ch >> 4;
        int kc = (ch & 15) * 8;
        *(f16x8*)&Hs[col * 136 + kc] = *(const f16x8*)&WTh[(long)(c0 + col) * 128 + kc];
        *(f16x8*)&Ls[col * 136 + kc] = *(const f16x8*)&WTl[(long)(c0 + col) * 128 + kc];
    }

    int wv = t >> 6, l = t & 63;
    int r0w = (b >> 1) * 64 + wv * 16;
    int arow = r0w + (l & 15);
    if (arow >= N) arow = N - 1;
    int kb = (l >> 4) * 8;

    f16x8 a[4];
#pragma unroll
    for (int ks = 0; ks < 4; ++ks)
        a[ks] = *(const f16x8*)&Bs[((long)ks * N_NODES + arow) * 32 + kb];
    __syncthreads();

    f32x4 acc[NCB];
#pragma unroll
    for (int cb = 0; cb < NCB; ++cb) acc[cb] = f32x4{0.f, 0.f, 0.f, 0.f};
#pragma unroll
    for (int ks = 0; ks < 4; ++ks) {
#pragma unroll
        for (int cb = 0; cb < NCB; ++cb) {
            int wi = (cb * 16 + (l & 15)) * 136 + ks * 32 + kb;
            f16x8 bh = *(const f16x8*)&Hs[wi];
            f16x8 bl = *(const f16x8*)&Ls[wi];
            acc[cb] = __builtin_amdgcn_mfma_f32_16x16x32_f16(a[ks], bh, acc[cb], 0, 0, 0);
            acc[cb] = __builtin_amdgcn_mfma_f32_16x16x32_f16(a[ks], bl, acc[cb], 0, 0, 0);
        }
    }
    int rbase = r0w + (l >> 4) * 4;
    float dv[4];
#pragma unroll
    for (int i = 0; i < 4; ++i) dv[i] = (rbase + i < N) ? dinv[rbase + i] : 0.f;
#pragma unroll
    for (int cb = 0; cb < NCB; ++cb) {
        int fc = c0 + cb * 16 + (l & 15);
        long sb = (long)(fc >> 5) * N_NODES * 32 + (fc & 31);
#pragma unroll
        for (int i = 0; i < 4; ++i) {
            int r = rbase + i;
            if (r < N) As[sb + (long)r * 32] = (f16)(acc[cb][i] * dv[i]);
        }
    }
}

// ---------------- sliced XCD-partitioned gather (M=128): A_s -> B_s ----------------
__global__ __launch_bounds__(256)
void k_gather128(const f16* __restrict__ As, const int* __restrict__ off,
                 const unsigned short* __restrict__ csr, const float* __restrict__ dinv,
                 const float* __restrict__ bias, f16* __restrict__ Bs) {
    int vb = blockIdx.x;
    int g = vb & 7, blk = vb >> 3;
    int t = threadIdx.x;
    int nl = blk * 64 + (t >> 2);
    if (nl >= 25000) return;
    int node = (g & 1) * 25000 + nl;
    int cs = g >> 1;
    int qq = (t & 3) * 8;
    const f16* Aq = As + (long)cs * N_NODES * 32 + qq;

    float acc[8];
    {
        f16x8 v = *(const f16x8*)&Aq[(long)node * 32];
#pragma unroll
        for (int c = 0; c < 8; ++c) acc[c] = (float)v[c];
    }
    int j = off[node], j1 = off[node + 1];
    for (; j + 8 <= j1; j += 8) {
        int s0 = csr[j + 0], s1 = csr[j + 1], s2 = csr[j + 2], s3 = csr[j + 3];
        int s4 = csr[j + 4], s5 = csr[j + 5], s6 = csr[j + 6], s7 = csr[j + 7];
        f16x8 v0 = *(const f16x8*)&Aq[(long)s0 * 32];
        f16x8 v1 = *(const f16x8*)&Aq[(long)s1 * 32];
        f16x8 v2 = *(const f16x8*)&Aq[(long)s2 * 32];
        f16x8 v3 = *(const f16x8*)&Aq[(long)s3 * 32];
        f16x8 v4 = *(const f16x8*)&Aq[(long)s4 * 32];
        f16x8 v5 = *(const f16x8*)&Aq[(long)s5 * 32];
        f16x8 v6 = *(const f16x8*)&Aq[(long)s6 * 32];
        f16x8 v7 = *(const f16x8*)&Aq[(long)s7 * 32];
#pragma unroll
        for (int c = 0; c < 8; ++c)
            acc[c] += ((float)v0[c] + (float)v1[c] + (float)v2[c] + (float)v3[c])
                    + ((float)v4[c] + (float)v5[c] + (float)v6[c] + (float)v7[c]);
    }
    for (; j + 2 <= j1; j += 2) {
        int s0 = csr[j + 0], s1 = csr[j + 1];
        f16x8 v0 = *(const f16x8*)&Aq[(long)s0 * 32];
        f16x8 v1 = *(const f16x8*)&Aq[(long)s1 * 32];
#pragma unroll
        for (int c = 0; c < 8; ++c) acc[c] += (float)v0[c] + (float)v1[c];
    }
    if (j < j1) {
        int s = csr[j];
        f16x8 v = *(const f16x8*)&Aq[(long)s * 32];
#pragma unroll
        for (int c = 0; c < 8; ++c) acc[c] += (float)v[c];
    }
    float sc = dinv[node];
    int q = cs * 32 + qq;
    float4 bb0 = *(const float4*)&bias[q];
    float4 bb1 = *(const float4*)&bias[q + 4];
    float bv[8] = {bb0.x, bb0.y, bb0.z, bb0.w, bb1.x, bb1.y, bb1.z, bb1.w};
    f16x8 o;
#pragma unroll
    for (int c = 0; c < 8; ++c) o[c] = (f16)fmaxf(acc[c] * sc + bv[c], 0.f);
    *(f16x8*)&Bs[((long)cs * N_NODES + node) * 32 + qq] = o;
}

// ---------------- sliced gather (M=64): A3_s (2 slices) -> z [node][64] f16 ----------
__global__ __launch_bounds__(256)
void k_gather64(const f16* __restrict__ As, const int* __restrict__ off,
                const unsigned short* __restrict__ csr, const float* __restrict__ dinv,
                const float* __restrict__ bias, f16* __restrict__ z) {
    int vb = blockIdx.x;
    int g = vb & 7, blk = vb >> 3;
    int t = threadIdx.x;
    int nl = blk * 64 + (t >> 2);
    if (nl >= 12500) return;
    int node = (g >> 1) * 12500 + nl;
    int cs = g & 1;
    int qq = (t & 3) * 8;
    const f16* Aq = As + (long)cs * N_NODES * 32 + qq;

    float acc[8];
    {
        f16x8 v = *(const f16x8*)&Aq[(long)node * 32];
#pragma unroll
        for (int c = 0; c < 8; ++c) acc[c] = (float)v[c];
    }
    int j = off[node], j1 = off[node + 1];
    for (; j + 8 <= j1; j += 8) {
        int s0 = csr[j + 0], s1 = csr[j + 1], s2 = csr[j + 2], s3 = csr[j + 3];
        int s4 = csr[j + 4], s5 = csr[j + 5], s6 = csr[j + 6], s7 = csr[j + 7];
        f16x8 v0 = *(const f16x8*)&Aq[(long)s0 * 32];
        f16x8 v1 = *(const f16x8*)&Aq[(long)s1 * 32];
        f16x8 v2 = *(const f16x8*)&Aq[(long)s2 * 32];
        f16x8 v3 = *(const f16x8*)&Aq[(long)s3 * 32];
        f16x8 v4 = *(const f16x8*)&Aq[(long)s4 * 32];
        f16x8 v5 = *(const f16x8*)&Aq[(long)s5 * 32];
        f16x8 v6 = *(const f16x8*)&Aq[(long)s6 * 32];
        f16x8 v7 = *(const f16x8*)&Aq[(long)s7 * 32];
#pragma unroll
        for (int c = 0; c < 8; ++c)
            acc[c] += ((float)v0[c] + (float)v1[c] + (float)v2[c] + (float)v3[c])
                    + ((float)v4[c] + (float)v5[c] + (float)v6[c] + (float)v7[c]);
    }
    for (; j + 2 <= j1; j += 2) {
        int s0 = csr[j + 0], s1 = csr[j + 1];
        f16x8 v0 = *(const f16x8*)&Aq[(long)s0 * 32];
        f16x8 v1 = *(const f16x8*)&Aq[(long)s1 * 32];
#pragma unroll
        for (int c = 0; c < 8; ++c) acc[c] += (float)v0[c] + (float)v1[c];
    }
    if (j < j1) {
        int s = csr[j];
        f16x8 v = *(const f16x8*)&Aq[(long)s * 32];
#pragma unroll
        for (int c = 0; c < 8; ++c) acc[c] += (float)v[c];
    }
    float sc = dinv[node];
    int q = cs * 32 + qq;
    float4 bb0 = *(const float4*)&bias[q];
    float4 bb1 = *(const float4*)&bias[q + 4];
    float bv[8] = {bb0.x, bb0.y, bb0.z, bb0.w, bb1.x, bb1.y, bb1.z, bb1.w};
    f16x8 o;
#pragma unroll
    for (int c = 0; c < 8; ++c) o[c] = (f16)(acc[c] * sc + bv[c]);
    *(f16x8*)&z[(long)node * 64 + q] = o;
}

// ---------------- decode: out[i] = dot64(z16[a], z16[b]); 8 thr/edge, f16x8 loads ------
__global__ __launch_bounds__(256)
void k_decode(const f16* __restrict__ z, const int* __restrict__ eli,
              float* __restrict__ out, int L) {
    int t = blockIdx.x * blockDim.x + threadIdx.x;
    int e = t >> 3;
    int lane = t & 7;
    if (e >= L) return;
    int a = eli[e], b = eli[L + e];
    f16x8 va = *(const f16x8*)&z[(long)a * 64 + lane * 8];
    f16x8 vb = *(const f16x8*)&z[(long)b * 64 + lane * 8];
    float s = 0.f;
#pragma unroll
    for (int c = 0; c < 8; ++c) s += (float)va[c] * (float)vb[c];
    s += __shfl_xor(s, 1, 8);
    s += __shfl_xor(s, 2, 8);
    s += __shfl_xor(s, 4, 8);
    if (lane == 0) out[e] = s;
}

extern "C" void kernel_launch(void* const* d_in, const int* in_sizes, int n_in,
                              void* d_out, int out_size, void* d_ws, size_t ws_size,
                              hipStream_t stream) {
    const float* x   = (const float*)d_in[0];
    const float* W1  = (const float*)d_in[1];
    const float* b1  = (const float*)d_in[2];
    const float* W2  = (const float*)d_in[3];
    const float* b2  = (const float*)d_in[4];
    const float* W3  = (const float*)d_in[5];
    const float* b3  = (const float*)d_in[6];
    const int*   ei  = (const int*)d_in[7];
    const int*   eli = (const int*)d_in[8];
    float* out = (float*)d_out;

    char* ws = (char*)d_ws;
    float* dinv = (float*)ws;                  ws += 50048 * 4;
    f16*   A    = (f16*)ws;                    ws += (long)N_NODES * 128 * 2;   // sliced
    f16*   B    = (f16*)ws;                    ws += (long)N_NODES * 128 * 2;   // sliced
    f16*   z    = (f16*)ws;                    ws += (long)N_NODES * 64 * 2;
    int*   cnt  = (int*)ws;                    ws += 50048 * 4;
    int*   cnt2 = (int*)ws;                    ws += 50048 * 4;   // contiguous with cnt
    int*   off  = (int*)ws;                    ws += 50048 * 4;
    unsigned short* csr = (unsigned short*)ws; ws += (long)N_EDGES * 2;
    int*   bsum = (int*)ws;                    ws += 256 * 4;
    f16*   WT1h = (f16*)ws;                    ws += 16384 * 2;
    f16*   WT1l = (f16*)ws;                    ws += 16384 * 2;
    f16*   WT2h = (f16*)ws;                    ws += 16384 * 2;
    f16*   WT2l = (f16*)ws;                    ws += 16384 * 2;
    f16*   WT3h = (f16*)ws;                    ws += 8192 * 2;
    f16*   WT3l = (f16*)ws;                    ws += 8192 * 2;

    const int* esrc = ei;
    const int* edst = ei + N_EDGES;

    const int NB = (N_NODES + 255) / 256;  // 196

    k_zero   <<<98, 256, 0, stream>>>((int4*)cnt, 25024);
    k_prep   <<<25064, 256, 0, stream>>>(W1, W2, W3, WT1h, WT1l, WT2h, WT2l,
                                         WT3h, WT3l, edst, cnt);
    k_partial<<<NB, 256, 0, stream>>>(cnt, dinv, bsum, N_NODES);
    k_offsets<<<NB, 256, 0, stream>>>(cnt, bsum, off, N_NODES, NB);
    k_bucket <<<25000, 256, 0, stream>>>(esrc, edst, off, cnt2, csr);

    // layer 1
    k_gemm1<<<ROW_BLOCKS * 2, 256, 0, stream>>>(x, WT1h, WT1l, dinv, A, N_NODES);
    k_gather128<<<391 * 8, 256, 0, stream>>>(A, off, csr, dinv, b1, B);
    // layer 2
    k_gemm23<128><<<ROW_BLOCKS * 2, 256, 0, stream>>>(B, WT2h, WT2l, dinv, A, N_NODES);
    k_gather128<<<391 * 8, 256, 0, stream>>>(A, off, csr, dinv, b2, B);
    // layer 3 (M=64, 2 slices, no relu, f16 z out)
    k_gemm23<64><<<ROW_BLOCKS * 2, 256, 0, stream>>>(B, WT3h, WT3l, dinv, A, N_NODES);
    k_gather64<<<196 * 8, 256, 0, stream>>>(A, off, csr, dinv, b3, z);

    // decode (8 thr/edge, f16x8 loads)
    k_decode<<<(N_LABEL * 8 + 255) / 256, 256, 0, stream>>>(z, eli, out, N_LABEL);
}